// Round 8
// baseline (246.922 us; speedup 1.0000x reference)
//
#include <hip/hip_runtime.h>
#include <hip/hip_bf16.h>
#include <math.h>

// Problem constants
#define B_   16
#define HID_ 1024
#define LH_  32
#define LD_  128
#define BLOCK_ 16
#define NBPS_  64
#define MAXLEN_ 1024
#define SPLIT_ 4
#define CHUNK_ (MAXLEN_ / SPLIT_)   // 256

typedef float vf4 __attribute__((ext_vector_type(4)));

// ------- fused q projection + RoPE ------------------------------------------
__global__ __launch_bounds__(256) void qproj_rope_kernel(const float* __restrict__ hs,
                                                         const float* __restrict__ w,
                                                         const int* __restrict__ pid,
                                                         const int* __restrict__ nsp,
                                                         float* __restrict__ q) {
    int t = threadIdx.x;
    int h = blockIdx.x >> 3;       // 32 heads
    int g = blockIdx.x & 7;        // 8 d-groups of 8
    __shared__ float shs[16 * 1024];       // 64 KB: all of hs
    __shared__ float ssum[16][16];         // [j<8: low half | j+8: high][b]
    {
        const vf4* src = (const vf4*)hs;
        vf4* dst = (vf4*)shs;
        for (int i = t; i < 4096; i += 256) dst[i] = src[i];
    }
    int j  = t >> 5;        // 0..7
    int sl = t & 31;
    int r0 = h * 128 + g * 8 + j;       // d = g*8+j in [0,64)
    int r1 = r0 + 64;
    vf4 w0[8], w1[8];
#pragma unroll
    for (int s = 0; s < 8; ++s) {
        w0[s] = *(const vf4*)&w[(size_t)r0 * HID_ + s * 128 + sl * 4];
        w1[s] = *(const vf4*)&w[(size_t)r1 * HID_ + s * 128 + sl * 4];
    }
    __syncthreads();
    for (int b = 0; b < B_; ++b) {
        float p0 = 0.f, p1 = 0.f;
#pragma unroll
        for (int s = 0; s < 8; ++s) {
            vf4 a = *(const vf4*)&shs[b * 1024 + s * 128 + sl * 4];
            p0 += w0[s].x*a.x + w0[s].y*a.y + w0[s].z*a.z + w0[s].w*a.w;
            p1 += w1[s].x*a.x + w1[s].y*a.y + w1[s].z*a.z + w1[s].w*a.w;
        }
#pragma unroll
        for (int o = 1; o < 32; o <<= 1) { p0 += __shfl_xor(p0, o); p1 += __shfl_xor(p1, o); }
        if (sl == 0) { ssum[j][b] = p0; ssum[j + 8][b] = p1; }
    }
    __syncthreads();
    if (t < 128) {
        int jj = t >> 4;       // 0..7
        int b  = t & 15;
        int d  = g * 8 + jj;
        double x0 = (double)ssum[jj][b];
        double x1 = (double)ssum[jj + 8][b];
        double pos = (double)(pid[b] + nsp[0]);
        double inv_freq = 1.0 / pow(10000.0, (double)d * (1.0 / 64.0));
        double f = pos * inv_freq;
        double cs = cos(f), sn = sin(f);
        const double scale = 0.08838834764831845;   // 1/sqrt(128)
        int base = b * 4096 + h * LD_ + d;
        q[base]      = (float)((x0 * cs - x1 * sn) * scale);
        q[base + 64] = (float)((x1 * cs + x0 * sn) * scale);
    }
}

// ---------------- flash-decode attention partials (round-6 online loop) -----
__global__ __launch_bounds__(256) void attn_kernel(const float* __restrict__ q,
                                                   const float* __restrict__ kc,
                                                   const float* __restrict__ vc,
                                                   const int* __restrict__ btab,
                                                   const int* __restrict__ slen,
                                                   float* __restrict__ pml,
                                                   float* __restrict__ pacc) {
    int c = blockIdx.x, h = blockIdx.y, b = blockIdx.z;
    int L = slen[b];
    int start = c * CHUNK_;
    int bh = b * LH_ + h;
    int pbase = bh * SPLIT_ + c;
    int t = threadIdx.x;

    if (start >= L) {
        if (t < 128) pacc[(size_t)pbase * 128 + t] = 0.f;
        if (t == 0) { pml[pbase * 2] = -INFINITY; pml[pbase * 2 + 1] = 0.f; }
        return;
    }

    int lane = t & 63, wv = t >> 6;
    int sg = lane >> 4;                 // subgroup 0..3 within wave
    int lg = lane & 15;
    int d0 = lg * 8;
    const float* qp = q + (size_t)bh * LD_ + d0;
    vf4 qa = *(const vf4*)qp;
    vf4 qb = *(const vf4*)(qp + 4);

    int end = min(start + CHUNK_, L);
    float m = -INFINITY, l = 0.f;
    float acc[8];
#pragma unroll
    for (int k = 0; k < 8; ++k) acc[k] = 0.f;

#pragma unroll 2
    for (int pos = start + wv * 4 + sg; pos < end; pos += 16) {
        int blk = btab[b * NBPS_ + (pos >> 4)];
        size_t off = (((size_t)blk * LH_ + h) * BLOCK_ + (pos & 15)) * LD_ + d0;
        vf4 k0 = *(const vf4*)(kc + off);
        vf4 k1 = *(const vf4*)(kc + off + 4);
        vf4 v0 = *(const vf4*)(vc + off);
        vf4 v1 = *(const vf4*)(vc + off + 4);

        float dot = qa.x*k0.x + qa.y*k0.y + qa.z*k0.z + qa.w*k0.w
                  + qb.x*k1.x + qb.y*k1.y + qb.z*k1.z + qb.w*k1.w;
#pragma unroll
        for (int o = 1; o < 16; o <<= 1) dot += __shfl_xor(dot, o);

        float mn = fmaxf(m, dot);
        float r = (m >= mn) ? 1.f : __expf(m - mn);
        float p = __expf(dot - mn);
        l = l * r + p;
        acc[0] = acc[0]*r + p*v0.x;  acc[1] = acc[1]*r + p*v0.y;
        acc[2] = acc[2]*r + p*v0.z;  acc[3] = acc[3]*r + p*v0.w;
        acc[4] = acc[4]*r + p*v1.x;  acc[5] = acc[5]*r + p*v1.y;
        acc[6] = acc[6]*r + p*v1.z;  acc[7] = acc[7]*r + p*v1.w;
        m = mn;
    }

    // merge the 4 16-lane groups within the wave
#pragma unroll
    for (int o = 16; o < 64; o <<= 1) {
        float m2 = __shfl_xor(m, o), l2 = __shfl_xor(l, o);
        float a2[8];
#pragma unroll
        for (int k = 0; k < 8; ++k) a2[k] = __shfl_xor(acc[k], o);
        float mn = fmaxf(m, m2);
        float ra = (m  >= mn) ? 1.f : __expf(m  - mn);
        float rb = (m2 >= mn) ? 1.f : __expf(m2 - mn);
        l = l * ra + l2 * rb;
#pragma unroll
        for (int k = 0; k < 8; ++k) acc[k] = acc[k]*ra + a2[k]*rb;
        m = mn;
    }

    __shared__ float sm[4], sl_[4], sacc[4][128];
    if (lane < 16) {
#pragma unroll
        for (int k = 0; k < 8; ++k) sacc[wv][d0 + k] = acc[k];
        if (lane == 0) { sm[wv] = m; sl_[wv] = l; }
    }
    __syncthreads();

    if (t < 64) {
        float M = fmaxf(fmaxf(sm[0], sm[1]), fmaxf(sm[2], sm[3]));
        int d = t * 2;
        float lt = 0.f, o0 = 0.f, o1 = 0.f;
#pragma unroll
        for (int w2 = 0; w2 < 4; ++w2) {
            float mw = sm[w2];
            float e = (mw >= M) ? 1.f : __expf(mw - M);
            lt += e * sl_[w2];
            o0 += e * sacc[w2][d];
            o1 += e * sacc[w2][d + 1];
        }
        pacc[(size_t)pbase * 128 + d]     = o0;
        pacc[(size_t)pbase * 128 + d + 1] = o1;
        if (t == 0) { pml[pbase * 2] = M; pml[pbase * 2 + 1] = lt; }
    }
}

// ---------------- combine chunk partials ------------------------------------
__global__ __launch_bounds__(64) void combine_kernel(const float* __restrict__ pml,
                                                     const float* __restrict__ pacc,
                                                     float* __restrict__ attn) {
    int bh = blockIdx.x;
    int lane = threadIdx.x;
    float M = -INFINITY;
#pragma unroll
    for (int c = 0; c < SPLIT_; ++c) M = fmaxf(M, pml[(bh * SPLIT_ + c) * 2]);
    int d = lane * 2;
    float lt = 0.f, o0 = 0.f, o1 = 0.f;
#pragma unroll
    for (int c = 0; c < SPLIT_; ++c) {
        float mc = pml[(bh * SPLIT_ + c) * 2];
        float e = (mc >= M) ? 1.f : __expf(mc - M);
        lt += e * pml[(bh * SPLIT_ + c) * 2 + 1];
        o0 += e * pacc[((size_t)bh * SPLIT_ + c) * 128 + d];
        o1 += e * pacc[((size_t)bh * SPLIT_ + c) * 128 + d + 1];
    }
    float inv = 1.f / lt;
    attn[(size_t)bh * LD_ + d]     = o0 * inv;
    attn[(size_t)bh * LD_ + d + 1] = o1 * inv;
}

// ---------------- o projection ----------------------------------------------
__global__ __launch_bounds__(256) void oproj_kernel(const float* __restrict__ attn,
                                                    const float* __restrict__ w,
                                                    float* __restrict__ out) {
    int t = threadIdx.x;
    int row0 = blockIdx.x * 4;          // 1024/4 = 256 blocks
    float wr[4][16];
#pragma unroll
    for (int r = 0; r < 4; ++r)
#pragma unroll
        for (int s = 0; s < 16; ++s)
            wr[r][s] = w[(size_t)(row0 + r) * 4096 + t + 256 * s];

    int lane = t & 63, wv = t >> 6;
    __shared__ float lds[16][4][4];     // [b][wave][row]
    for (int b = 0; b < B_; ++b) {
        float p[4] = {0.f, 0.f, 0.f, 0.f};
#pragma unroll
        for (int s = 0; s < 16; ++s) {
            float a = attn[b * 4096 + t + 256 * s];
#pragma unroll
            for (int r = 0; r < 4; ++r) p[r] += wr[r][s] * a;
        }
#pragma unroll
        for (int off = 32; off; off >>= 1)
#pragma unroll
            for (int r = 0; r < 4; ++r) p[r] += __shfl_xor(p[r], off);
        if (lane == 0)
#pragma unroll
            for (int r = 0; r < 4; ++r) lds[b][wv][r] = p[r];
    }
    __syncthreads();
    if (t < 64) {
        int b = t >> 2, r = t & 3;
        out[b * HID_ + row0 + r] = lds[b][0][r] + lds[b][1][r] + lds[b][2][r] + lds[b][3][r];
    }
}

extern "C" void kernel_launch(void* const* d_in, const int* in_sizes, int n_in,
                              void* d_out, int out_size, void* d_ws, size_t ws_size,
                              hipStream_t stream) {
    const float* hs   = (const float*)d_in[0];
    const float* qw   = (const float*)d_in[1];
    const float* ow   = (const float*)d_in[2];
    const float* kc   = (const float*)d_in[3];
    const float* vc   = (const float*)d_in[4];
    const int*   btab = (const int*)d_in[5];
    const int*   slen = (const int*)d_in[6];
    const int*   pid  = (const int*)d_in[7];
    const int*   nsp  = (const int*)d_in[8];
    float* out = (float*)d_out;
    float* ws  = (float*)d_ws;

    float* q_ws    = ws;            // 65536 floats
    float* attn_ws = ws + 65536;    // 65536 floats
    float* pml     = ws + 131072;   // 512*4*2   = 4096 floats
    float* pacc    = ws + 139264;   // 512*4*128 = 262144 floats
    // DIAGNOSTIC: dead duplicate outputs to time attn by delta
    float* pml2    = ws + 401408;
    float* pacc2   = ws + 409600;
    float* pml3    = ws + 671744;
    float* pacc3   = ws + 679936;

    qproj_rope_kernel<<<256, 256, 0, stream>>>(hs, qw, pid, nsp, q_ws);
    attn_kernel<<<dim3(SPLIT_, LH_, B_), 256, 0, stream>>>(q_ws, kc, vc, btab, slen, pml, pacc);
    // DIAGNOSTIC duplicates (outputs unused): attn_time = (dur - base) / 2
    attn_kernel<<<dim3(SPLIT_, LH_, B_), 256, 0, stream>>>(q_ws, kc, vc, btab, slen, pml2, pacc2);
    attn_kernel<<<dim3(SPLIT_, LH_, B_), 256, 0, stream>>>(q_ws, kc, vc, btab, slen, pml3, pacc3);
    combine_kernel<<<B_ * LH_, 64, 0, stream>>>(pml, pacc, attn_ws);
    oproj_kernel<<<256, 256, 0, stream>>>(attn_ws, ow, out);
}

// Round 9
// 174.521 us; speedup vs baseline: 1.4149x; 1.4149x over previous
//
#include <hip/hip_runtime.h>
#include <hip/hip_bf16.h>
#include <math.h>

// Problem constants
#define B_   16
#define HID_ 1024
#define LH_  32
#define LD_  128
#define BLOCK_ 16
#define NBPS_  64
#define MAXLEN_ 1024
#define SPLIT_ 16
#define CHUNK_ (MAXLEN_ / SPLIT_)   // 64
#define NITEMS_ (SPLIT_ * LH_ * B_) // 8192
#define NBLOCKS_ 2048               // exactly-resident: 256 CU x 8 blocks

typedef float vf4 __attribute__((ext_vector_type(4)));

// ------- fused q projection + RoPE (+ work-queue counter reset) -------------
__global__ __launch_bounds__(256) void qproj_rope_kernel(const float* __restrict__ hs,
                                                         const float* __restrict__ w,
                                                         const int* __restrict__ pid,
                                                         const int* __restrict__ nsp,
                                                         float* __restrict__ q,
                                                         int* __restrict__ cnt) {
    int t = threadIdx.x;
    if (blockIdx.x == 0 && t == 0) *cnt = 0;   // queue reset for attn (runs before attn)
    int h = blockIdx.x >> 3;       // 32 heads
    int g = blockIdx.x & 7;        // 8 d-groups of 8
    __shared__ float shs[16 * 1024];       // 64 KB: all of hs
    __shared__ float ssum[16][16];         // [j<8: low half | j+8: high][b]
    {
        const vf4* src = (const vf4*)hs;
        vf4* dst = (vf4*)shs;
        for (int i = t; i < 4096; i += 256) dst[i] = src[i];
    }
    int j  = t >> 5;        // 0..7
    int sl = t & 31;
    int r0 = h * 128 + g * 8 + j;       // d = g*8+j in [0,64)
    int r1 = r0 + 64;
    vf4 w0[8], w1[8];
#pragma unroll
    for (int s = 0; s < 8; ++s) {
        w0[s] = *(const vf4*)&w[(size_t)r0 * HID_ + s * 128 + sl * 4];
        w1[s] = *(const vf4*)&w[(size_t)r1 * HID_ + s * 128 + sl * 4];
    }
    __syncthreads();
    for (int b = 0; b < B_; ++b) {
        float p0 = 0.f, p1 = 0.f;
#pragma unroll
        for (int s = 0; s < 8; ++s) {
            vf4 a = *(const vf4*)&shs[b * 1024 + s * 128 + sl * 4];
            p0 += w0[s].x*a.x + w0[s].y*a.y + w0[s].z*a.z + w0[s].w*a.w;
            p1 += w1[s].x*a.x + w1[s].y*a.y + w1[s].z*a.z + w1[s].w*a.w;
        }
#pragma unroll
        for (int o = 1; o < 32; o <<= 1) { p0 += __shfl_xor(p0, o); p1 += __shfl_xor(p1, o); }
        if (sl == 0) { ssum[j][b] = p0; ssum[j + 8][b] = p1; }
    }
    __syncthreads();
    if (t < 128) {
        int jj = t >> 4;       // 0..7
        int b  = t & 15;
        int d  = g * 8 + jj;
        double x0 = (double)ssum[jj][b];
        double x1 = (double)ssum[jj + 8][b];
        double pos = (double)(pid[b] + nsp[0]);
        double inv_freq = 1.0 / pow(10000.0, (double)d * (1.0 / 64.0));
        double f = pos * inv_freq;
        double cs = cos(f), sn = sin(f);
        const double scale = 0.08838834764831845;   // 1/sqrt(128)
        int base = b * 4096 + h * LD_ + d;
        q[base]      = (float)((x0 * cs - x1 * sn) * scale);
        q[base + 64] = (float)((x1 * cs + x0 * sn) * scale);
    }
}

// ------- flash-decode attention partials: dynamic work queue ----------------
// 2048 resident blocks pop (b,h,c) items (CHUNK=64) until the queue drains.
__global__ __launch_bounds__(256) void attn_kernel(const float* __restrict__ q,
                                                   const float* __restrict__ kc,
                                                   const float* __restrict__ vc,
                                                   const int* __restrict__ btab,
                                                   const int* __restrict__ slen,
                                                   float* __restrict__ pml,
                                                   float* __restrict__ pacc,
                                                   int* __restrict__ cnt) {
    int t = threadIdx.x;
    int lane = t & 63, wv = t >> 6;
    int sg = lane >> 4;                 // subgroup 0..3 within wave
    int lg = lane & 15;
    int d0 = lg * 8;
    int po = wv * 4 + sg;               // this thread's position offset in [0,16)

    __shared__ int sitem;
    __shared__ float sm[4], sl_[4], sacc[4][128];

    while (true) {
        if (t == 0) sitem = atomicAdd(cnt, 1);
        __syncthreads();
        int item = sitem;
        if (item >= NITEMS_) break;

        int c = item & (SPLIT_ - 1);
        int h = (item >> 4) & (LH_ - 1);
        int b = item >> 9;
        int L = slen[b];
        int start = c * CHUNK_;
        int bh = b * LH_ + h;
        int pbase = bh * SPLIT_ + c;

        if (start >= L) {
            if (t < 128) pacc[(size_t)pbase * 128 + t] = 0.f;
            if (t == 0) { pml[pbase * 2] = -INFINITY; pml[pbase * 2 + 1] = 0.f; }
            __syncthreads();
            continue;
        }

        const float* qp = q + (size_t)bh * LD_ + d0;
        vf4 qa = *(const vf4*)qp;
        vf4 qb = *(const vf4*)(qp + 4);

        int end = min(start + CHUNK_, L);
        float m = -INFINITY, l = 0.f;
        float acc[8];
#pragma unroll
        for (int k = 0; k < 8; ++k) acc[k] = 0.f;

#pragma unroll 2
        for (int pos = start + po; pos < end; pos += 16) {
            int blk = btab[b * NBPS_ + (pos >> 4)];
            size_t off = (((size_t)blk * LH_ + h) * BLOCK_ + (pos & 15)) * LD_ + d0;
            vf4 k0 = *(const vf4*)(kc + off);
            vf4 k1 = *(const vf4*)(kc + off + 4);
            vf4 v0 = *(const vf4*)(vc + off);
            vf4 v1 = *(const vf4*)(vc + off + 4);

            float dot = qa.x*k0.x + qa.y*k0.y + qa.z*k0.z + qa.w*k0.w
                      + qb.x*k1.x + qb.y*k1.y + qb.z*k1.z + qb.w*k1.w;
#pragma unroll
            for (int o = 1; o < 16; o <<= 1) dot += __shfl_xor(dot, o);

            float mn = fmaxf(m, dot);
            float r = (m >= mn) ? 1.f : __expf(m - mn);
            float p = __expf(dot - mn);
            l = l * r + p;
            acc[0] = acc[0]*r + p*v0.x;  acc[1] = acc[1]*r + p*v0.y;
            acc[2] = acc[2]*r + p*v0.z;  acc[3] = acc[3]*r + p*v0.w;
            acc[4] = acc[4]*r + p*v1.x;  acc[5] = acc[5]*r + p*v1.y;
            acc[6] = acc[6]*r + p*v1.z;  acc[7] = acc[7]*r + p*v1.w;
            m = mn;
        }

        // merge the 4 16-lane groups within the wave
#pragma unroll
        for (int o = 16; o < 64; o <<= 1) {
            float m2 = __shfl_xor(m, o), l2 = __shfl_xor(l, o);
            float a2[8];
#pragma unroll
            for (int k = 0; k < 8; ++k) a2[k] = __shfl_xor(acc[k], o);
            float mn = fmaxf(m, m2);
            float ra = (m  >= mn) ? 1.f : __expf(m  - mn);
            float rb = (m2 >= mn) ? 1.f : __expf(m2 - mn);
            l = l * ra + l2 * rb;
#pragma unroll
            for (int k = 0; k < 8; ++k) acc[k] = acc[k]*ra + a2[k]*rb;
            m = mn;
        }

        if (lane < 16) {
#pragma unroll
            for (int k = 0; k < 8; ++k) sacc[wv][d0 + k] = acc[k];
            if (lane == 0) { sm[wv] = m; sl_[wv] = l; }
        }
        __syncthreads();

        if (t < 64) {
            float M = fmaxf(fmaxf(sm[0], sm[1]), fmaxf(sm[2], sm[3]));
            int d = t * 2;
            float lt = 0.f, o0 = 0.f, o1 = 0.f;
#pragma unroll
            for (int w2 = 0; w2 < 4; ++w2) {
                float mw = sm[w2];
                float e = (mw >= M) ? 1.f : __expf(mw - M);
                lt += e * sl_[w2];
                o0 += e * sacc[w2][d];
                o1 += e * sacc[w2][d + 1];
            }
            pacc[(size_t)pbase * 128 + d]     = o0;
            pacc[(size_t)pbase * 128 + d + 1] = o1;
            if (t == 0) { pml[pbase * 2] = M; pml[pbase * 2 + 1] = lt; }
        }
        __syncthreads();   // protect sitem/sacc before next pop
    }
}

// ---------------- combine chunk partials ------------------------------------
__global__ __launch_bounds__(64) void combine_kernel(const float* __restrict__ pml,
                                                     const float* __restrict__ pacc,
                                                     float* __restrict__ attn) {
    int bh = blockIdx.x;
    int lane = threadIdx.x;
    float M = -INFINITY;
#pragma unroll
    for (int c = 0; c < SPLIT_; ++c) M = fmaxf(M, pml[(bh * SPLIT_ + c) * 2]);
    int d = lane * 2;
    float lt = 0.f, o0 = 0.f, o1 = 0.f;
#pragma unroll
    for (int c = 0; c < SPLIT_; ++c) {
        float mc = pml[(bh * SPLIT_ + c) * 2];
        float e = (mc >= M) ? 1.f : __expf(mc - M);
        lt += e * pml[(bh * SPLIT_ + c) * 2 + 1];
        o0 += e * pacc[((size_t)bh * SPLIT_ + c) * 128 + d];
        o1 += e * pacc[((size_t)bh * SPLIT_ + c) * 128 + d + 1];
    }
    float inv = 1.f / lt;
    attn[(size_t)bh * LD_ + d]     = o0 * inv;
    attn[(size_t)bh * LD_ + d + 1] = o1 * inv;
}

// ---------------- o projection ----------------------------------------------
__global__ __launch_bounds__(256) void oproj_kernel(const float* __restrict__ attn,
                                                    const float* __restrict__ w,
                                                    float* __restrict__ out) {
    int t = threadIdx.x;
    int row0 = blockIdx.x * 4;          // 1024/4 = 256 blocks
    float wr[4][16];
#pragma unroll
    for (int r = 0; r < 4; ++r)
#pragma unroll
        for (int s = 0; s < 16; ++s)
            wr[r][s] = w[(size_t)(row0 + r) * 4096 + t + 256 * s];

    int lane = t & 63, wv = t >> 6;
    __shared__ float lds[16][4][4];     // [b][wave][row]
    for (int b = 0; b < B_; ++b) {
        float p[4] = {0.f, 0.f, 0.f, 0.f};
#pragma unroll
        for (int s = 0; s < 16; ++s) {
            float a = attn[b * 4096 + t + 256 * s];
#pragma unroll
            for (int r = 0; r < 4; ++r) p[r] += wr[r][s] * a;
        }
#pragma unroll
        for (int off = 32; off; off >>= 1)
#pragma unroll
            for (int r = 0; r < 4; ++r) p[r] += __shfl_xor(p[r], off);
        if (lane == 0)
#pragma unroll
            for (int r = 0; r < 4; ++r) lds[b][wv][r] = p[r];
    }
    __syncthreads();
    if (t < 64) {
        int b = t >> 2, r = t & 3;
        out[b * HID_ + row0 + r] = lds[b][0][r] + lds[b][1][r] + lds[b][2][r] + lds[b][3][r];
    }
}

extern "C" void kernel_launch(void* const* d_in, const int* in_sizes, int n_in,
                              void* d_out, int out_size, void* d_ws, size_t ws_size,
                              hipStream_t stream) {
    const float* hs   = (const float*)d_in[0];
    const float* qw   = (const float*)d_in[1];
    const float* ow   = (const float*)d_in[2];
    const float* kc   = (const float*)d_in[3];
    const float* vc   = (const float*)d_in[4];
    const int*   btab = (const int*)d_in[5];
    const int*   slen = (const int*)d_in[6];
    const int*   pid  = (const int*)d_in[7];
    const int*   nsp  = (const int*)d_in[8];
    float* out = (float*)d_out;
    float* ws  = (float*)d_ws;

    float* q_ws    = ws;            // 65536 floats
    float* attn_ws = ws + 65536;    // 65536 floats
    int*   cnt     = (int*)(ws + 131072);   // 256-float slot
    float* pml     = ws + 131328;   // 512*16*2   = 16384 floats
    float* pacc    = ws + 147712;   // 512*16*128 = 1048576 floats (4 MB)

    qproj_rope_kernel<<<256, 256, 0, stream>>>(hs, qw, pid, nsp, q_ws, cnt);
    attn_kernel<<<NBLOCKS_, 256, 0, stream>>>(q_ws, kc, vc, btab, slen, pml, pacc, cnt);
    combine_kernel<<<B_ * LH_, 64, 0, stream>>>(pml, pacc, attn_ws);
    oproj_kernel<<<256, 256, 0, stream>>>(attn_ws, ow, out);
}

// Round 10
// 109.641 us; speedup vs baseline: 2.2521x; 1.5917x over previous
//
#include <hip/hip_runtime.h>
#include <hip/hip_bf16.h>
#include <math.h>

// Problem constants
#define B_   16
#define HID_ 1024
#define LH_  32
#define LD_  128
#define BLOCK_ 16
#define NBPS_  64
#define MAXLEN_ 1024
#define SPLIT_ 16
#define CHUNK_ (MAXLEN_ / SPLIT_)   // 64

typedef float vf4 __attribute__((ext_vector_type(4)));

// ------- fused q projection + RoPE ------------------------------------------
__global__ __launch_bounds__(256) void qproj_rope_kernel(const float* __restrict__ hs,
                                                         const float* __restrict__ w,
                                                         const int* __restrict__ pid,
                                                         const int* __restrict__ nsp,
                                                         float* __restrict__ q) {
    int t = threadIdx.x;
    int h = blockIdx.x >> 3;       // 32 heads
    int g = blockIdx.x & 7;        // 8 d-groups of 8
    __shared__ float shs[16 * 1024];       // 64 KB: all of hs
    __shared__ float ssum[16][16];         // [j<8: low half | j+8: high][b]
    {
        const vf4* src = (const vf4*)hs;
        vf4* dst = (vf4*)shs;
        for (int i = t; i < 4096; i += 256) dst[i] = src[i];
    }
    int j  = t >> 5;        // 0..7
    int sl = t & 31;
    int r0 = h * 128 + g * 8 + j;       // d = g*8+j in [0,64)
    int r1 = r0 + 64;
    vf4 w0[8], w1[8];
#pragma unroll
    for (int s = 0; s < 8; ++s) {
        w0[s] = *(const vf4*)&w[(size_t)r0 * HID_ + s * 128 + sl * 4];
        w1[s] = *(const vf4*)&w[(size_t)r1 * HID_ + s * 128 + sl * 4];
    }
    __syncthreads();
    for (int b = 0; b < B_; ++b) {
        float p0 = 0.f, p1 = 0.f;
#pragma unroll
        for (int s = 0; s < 8; ++s) {
            vf4 a = *(const vf4*)&shs[b * 1024 + s * 128 + sl * 4];
            p0 += w0[s].x*a.x + w0[s].y*a.y + w0[s].z*a.z + w0[s].w*a.w;
            p1 += w1[s].x*a.x + w1[s].y*a.y + w1[s].z*a.z + w1[s].w*a.w;
        }
#pragma unroll
        for (int o = 1; o < 32; o <<= 1) { p0 += __shfl_xor(p0, o); p1 += __shfl_xor(p1, o); }
        if (sl == 0) { ssum[j][b] = p0; ssum[j + 8][b] = p1; }
    }
    __syncthreads();
    if (t < 128) {
        int jj = t >> 4;       // 0..7
        int b  = t & 15;
        int d  = g * 8 + jj;
        double x0 = (double)ssum[jj][b];
        double x1 = (double)ssum[jj + 8][b];
        double pos = (double)(pid[b] + nsp[0]);
        double inv_freq = 1.0 / pow(10000.0, (double)d * (1.0 / 64.0));
        double f = pos * inv_freq;
        double cs = cos(f), sn = sin(f);
        const double scale = 0.08838834764831845;   // 1/sqrt(128)
        int base = b * 4096 + h * LD_ + d;
        q[base]      = (float)((x0 * cs - x1 * sn) * scale);
        q[base + 64] = (float)((x1 * cs + x0 * sn) * scale);
    }
}

// ------- flash-decode attention partials: static fine grid (HW backfill) ----
__global__ __launch_bounds__(256) void attn_kernel(const float* __restrict__ q,
                                                   const float* __restrict__ kc,
                                                   const float* __restrict__ vc,
                                                   const int* __restrict__ btab,
                                                   const int* __restrict__ slen,
                                                   float* __restrict__ pml,
                                                   float* __restrict__ pacc) {
    int c = blockIdx.x, h = blockIdx.y, b = blockIdx.z;
    int L = slen[b];
    int start = c * CHUNK_;
    int bh = b * LH_ + h;
    int pbase = bh * SPLIT_ + c;
    int t = threadIdx.x;

    if (start >= L) {
        if (t < 128) pacc[(size_t)pbase * 128 + t] = 0.f;
        if (t == 0) { pml[pbase * 2] = -INFINITY; pml[pbase * 2 + 1] = 0.f; }
        return;
    }

    int lane = t & 63, wv = t >> 6;
    int sg = lane >> 4;                 // subgroup 0..3 within wave
    int lg = lane & 15;
    int d0 = lg * 8;
    int po = wv * 4 + sg;               // position offset in [0,16); pos&15 == po
    const float* qp = q + (size_t)bh * LD_ + d0;
    vf4 qa = *(const vf4*)qp;
    vf4 qb = *(const vf4*)(qp + 4);

    int end = min(start + CHUNK_, L);
    // lane-uniform cache-block ids for this chunk, hoisted
    int blkr[4];
#pragma unroll
    for (int i = 0; i < 4; ++i) blkr[i] = btab[b * NBPS_ + c * 4 + i];

    float m = -INFINITY, l = 0.f;
    float acc[8];
#pragma unroll
    for (int k = 0; k < 8; ++k) acc[k] = 0.f;

    int i = 0;
#pragma unroll 4
    for (int pos = start + po; pos < end; pos += 16, ++i) {
        size_t off = (((size_t)blkr[i] * LH_ + h) * BLOCK_ + po) * LD_ + d0;
        vf4 k0 = *(const vf4*)(kc + off);
        vf4 k1 = *(const vf4*)(kc + off + 4);
        vf4 v0 = *(const vf4*)(vc + off);
        vf4 v1 = *(const vf4*)(vc + off + 4);

        float dot = qa.x*k0.x + qa.y*k0.y + qa.z*k0.z + qa.w*k0.w
                  + qb.x*k1.x + qb.y*k1.y + qb.z*k1.z + qb.w*k1.w;
#pragma unroll
        for (int o = 1; o < 16; o <<= 1) dot += __shfl_xor(dot, o);

        float mn = fmaxf(m, dot);
        float r = (m >= mn) ? 1.f : __expf(m - mn);
        float p = __expf(dot - mn);
        l = l * r + p;
        acc[0] = acc[0]*r + p*v0.x;  acc[1] = acc[1]*r + p*v0.y;
        acc[2] = acc[2]*r + p*v0.z;  acc[3] = acc[3]*r + p*v0.w;
        acc[4] = acc[4]*r + p*v1.x;  acc[5] = acc[5]*r + p*v1.y;
        acc[6] = acc[6]*r + p*v1.z;  acc[7] = acc[7]*r + p*v1.w;
        m = mn;
    }

    // merge the 4 16-lane groups within the wave
#pragma unroll
    for (int o = 16; o < 64; o <<= 1) {
        float m2 = __shfl_xor(m, o), l2 = __shfl_xor(l, o);
        float a2[8];
#pragma unroll
        for (int k = 0; k < 8; ++k) a2[k] = __shfl_xor(acc[k], o);
        float mn = fmaxf(m, m2);
        float ra = (m  >= mn) ? 1.f : __expf(m  - mn);
        float rb = (m2 >= mn) ? 1.f : __expf(m2 - mn);
        l = l * ra + l2 * rb;
#pragma unroll
        for (int k = 0; k < 8; ++k) acc[k] = acc[k]*ra + a2[k]*rb;
        m = mn;
    }

    __shared__ float sm[4], sl_[4], sacc[4][128];
    if (lane < 16) {
#pragma unroll
        for (int k = 0; k < 8; ++k) sacc[wv][d0 + k] = acc[k];
        if (lane == 0) { sm[wv] = m; sl_[wv] = l; }
    }
    __syncthreads();

    if (t < 64) {
        float M = fmaxf(fmaxf(sm[0], sm[1]), fmaxf(sm[2], sm[3]));
        int d = t * 2;
        float lt = 0.f, o0 = 0.f, o1 = 0.f;
#pragma unroll
        for (int w2 = 0; w2 < 4; ++w2) {
            float mw = sm[w2];
            float e = (mw >= M) ? 1.f : __expf(mw - M);
            lt += e * sl_[w2];
            o0 += e * sacc[w2][d];
            o1 += e * sacc[w2][d + 1];
        }
        pacc[(size_t)pbase * 128 + d]     = o0;
        pacc[(size_t)pbase * 128 + d + 1] = o1;
        if (t == 0) { pml[pbase * 2] = M; pml[pbase * 2 + 1] = lt; }
    }
}

// ---------------- combine chunk partials ------------------------------------
__global__ __launch_bounds__(64) void combine_kernel(const float* __restrict__ pml,
                                                     const float* __restrict__ pacc,
                                                     float* __restrict__ attn) {
    int bh = blockIdx.x;
    int lane = threadIdx.x;
    float M = -INFINITY;
#pragma unroll
    for (int c = 0; c < SPLIT_; ++c) M = fmaxf(M, pml[(bh * SPLIT_ + c) * 2]);
    int d = lane * 2;
    float lt = 0.f, o0 = 0.f, o1 = 0.f;
#pragma unroll
    for (int c = 0; c < SPLIT_; ++c) {
        float mc = pml[(bh * SPLIT_ + c) * 2];
        float e = (mc >= M) ? 1.f : __expf(mc - M);
        lt += e * pml[(bh * SPLIT_ + c) * 2 + 1];
        o0 += e * pacc[((size_t)bh * SPLIT_ + c) * 128 + d];
        o1 += e * pacc[((size_t)bh * SPLIT_ + c) * 128 + d + 1];
    }
    float inv = 1.f / lt;
    attn[(size_t)bh * LD_ + d]     = o0 * inv;
    attn[(size_t)bh * LD_ + d + 1] = o1 * inv;
}

// ---------------- o projection ----------------------------------------------
__global__ __launch_bounds__(256) void oproj_kernel(const float* __restrict__ attn,
                                                    const float* __restrict__ w,
                                                    float* __restrict__ out) {
    int t = threadIdx.x;
    int row0 = blockIdx.x * 4;          // 1024/4 = 256 blocks
    float wr[4][16];
#pragma unroll
    for (int r = 0; r < 4; ++r)
#pragma unroll
        for (int s = 0; s < 16; ++s)
            wr[r][s] = w[(size_t)(row0 + r) * 4096 + t + 256 * s];

    int lane = t & 63, wv = t >> 6;
    __shared__ float lds[16][4][4];     // [b][wave][row]
    for (int b = 0; b < B_; ++b) {
        float p[4] = {0.f, 0.f, 0.f, 0.f};
#pragma unroll
        for (int s = 0; s < 16; ++s) {
            float a = attn[b * 4096 + t + 256 * s];
#pragma unroll
            for (int r = 0; r < 4; ++r) p[r] += wr[r][s] * a;
        }
#pragma unroll
        for (int off = 32; off; off >>= 1)
#pragma unroll
            for (int r = 0; r < 4; ++r) p[r] += __shfl_xor(p[r], off);
        if (lane == 0)
#pragma unroll
            for (int r = 0; r < 4; ++r) lds[b][wv][r] = p[r];
    }
    __syncthreads();
    if (t < 64) {
        int b = t >> 2, r = t & 3;
        out[b * HID_ + row0 + r] = lds[b][0][r] + lds[b][1][r] + lds[b][2][r] + lds[b][3][r];
    }
}

extern "C" void kernel_launch(void* const* d_in, const int* in_sizes, int n_in,
                              void* d_out, int out_size, void* d_ws, size_t ws_size,
                              hipStream_t stream) {
    const float* hs   = (const float*)d_in[0];
    const float* qw   = (const float*)d_in[1];
    const float* ow   = (const float*)d_in[2];
    const float* kc   = (const float*)d_in[3];
    const float* vc   = (const float*)d_in[4];
    const int*   btab = (const int*)d_in[5];
    const int*   slen = (const int*)d_in[6];
    const int*   pid  = (const int*)d_in[7];
    const int*   nsp  = (const int*)d_in[8];
    float* out = (float*)d_out;
    float* ws  = (float*)d_ws;

    float* q_ws    = ws;            // 65536 floats
    float* attn_ws = ws + 65536;    // 65536 floats
    float* pml     = ws + 131072;   // 512*16*2   = 16384 floats
    float* pacc    = ws + 147456;   // 512*16*128 = 1048576 floats (4 MB)

    qproj_rope_kernel<<<256, 256, 0, stream>>>(hs, qw, pid, nsp, q_ws);
    attn_kernel<<<dim3(SPLIT_, LH_, B_), 256, 0, stream>>>(q_ws, kc, vc, btab, slen, pml, pacc);
    combine_kernel<<<B_ * LH_, 64, 0, stream>>>(pml, pacc, attn_ws);
    oproj_kernel<<<256, 256, 0, stream>>>(attn_ws, ow, out);
}